// Round 9
// baseline (293.765 us; speedup 1.0000x reference)
//
#include <hip/hip_runtime.h>
#include <math.h>

#define IMG_H 1080
#define IMG_W 1920
#define NFLOW 5
#define HW (IMG_H * IMG_W)

#define TILE_W 64
#define TILE_H 32
#define HALO 24
#define REG_W (TILE_W + 2 * HALO)   // 112
#define REG_H (TILE_H + 2 * HALO)   // 80
#define THREADS 512
#define GRID_X (IMG_W / TILE_W)                 // 30
#define GRID_Y ((IMG_H + TILE_H - 1) / TILE_H)  // 34
#define NBLOCKS (GRID_X * GRID_Y)               // 1020

__device__ __forceinline__ unsigned pack3(float a, float b, float c) {
    const unsigned c0 = (unsigned)(int)(a + 0.5f);
    const unsigned c1 = (unsigned)(int)(b + 0.5f);
    const unsigned c2 = (unsigned)(int)(c + 0.5f);
    return c0 | (c1 << 8) | (c2 << 16);
}

// ---------- pre-pass: pack frame1 [3][H][W] f32 -> [H][W] u32 (u8 RGB), 4 px/thread ----------
__global__ __launch_bounds__(256) void pack_u8_kernel(const float* __restrict__ f1,
                                                      uint4* __restrict__ img4)
{
    const int q = blockIdx.x * 256 + threadIdx.x;   // quad index; HW % 4 == 0
    if (q >= HW / 4) return;
    const int gp = q * 4;
    const float4 c0 = *(const float4*)(f1 + gp);
    const float4 c1 = *(const float4*)(f1 + HW + gp);
    const float4 c2 = *(const float4*)(f1 + 2 * HW + gp);
    uint4 ov;
    ov.x = pack3(c0.x, c1.x, c2.x);
    ov.y = pack3(c0.y, c1.y, c2.y);
    ov.z = pack3(c0.z, c1.z, c2.z);
    ov.w = pack3(c0.w, c1.w, c2.w);
    img4[q] = ov;
}

// ---------- main: LDS-tiled warped-SSE, clustered loads, fused finalize ----------
__global__ __launch_bounds__(THREADS, 8) void psnr_mega_kernel(
    const float2* __restrict__ flow,        // [N][H][W] float2
    const unsigned int* __restrict__ img,   // [H][W] packed u8 RGB
    const float* __restrict__ f2,           // [3][H][W]
    float* __restrict__ sums,               // [5] zeroed
    unsigned int* __restrict__ counter,     // [1] zeroed
    float* __restrict__ out)                // [1]
{
    __shared__ __align__(16) unsigned int tile[REG_H * REG_W];  // 35840 B
    __shared__ float sacc[NFLOW][THREADS / 64];

    // --- bijective XCD-chunked swizzle (1020 = 8*127 + 4) ---
    const int wg = blockIdx.x;
    const int xcd = wg & 7;
    const int idx = wg >> 3;
    const int q = NBLOCKS >> 3;        // 127
    const int rr = NBLOCKS & 7;        // 4
    const int wgid = (xcd < rr ? xcd * (q + 1) : rr * (q + 1) + (xcd - rr) * q) + idx;
    const int tyb = wgid / GRID_X;
    const int txb = wgid - tyb * GRID_X;

    const int tx0 = txb * TILE_W;
    const int ty0 = tyb * TILE_H;
    const int bx = tx0 - HALO;
    const int by = ty0 - HALO;
    const int tid = threadIdx.x;

    // --- stage packed-u8 tile from img: 1 uint4 load per 4 texels ---
    for (int qi = tid; qi < (REG_H * REG_W) / 4; qi += THREADS) {
        const int ry = qi / (REG_W / 4);
        const int rx = (qi - ry * (REG_W / 4)) * 4;
        const int gy = by + ry;
        const int gx0 = bx + rx;
        uint4 ov = {0u, 0u, 0u, 0u};
        if ((unsigned)gy < (unsigned)IMG_H) {
            if (gx0 >= 0 && gx0 + 3 < IMG_W) {
                ov = *(const uint4*)(img + gy * IMG_W + gx0);   // bx%4==0 -> aligned
            } else {
#pragma unroll
                for (int j = 0; j < 4; ++j) {
                    const int gx = gx0 + j;
                    unsigned v = 0u;
                    if ((unsigned)gx < (unsigned)IMG_W) v = img[gy * IMG_W + gx];
                    ((unsigned*)&ov)[j] = v;
                }
            }
        }
        *(uint4*)&tile[ry * REG_W + rx] = ov;   // ds_write_b128, 16B-aligned
    }
    __syncthreads();

    float acc[NFLOW];
#pragma unroll
    for (int n = 0; n < NFLOW; ++n) acc[n] = 0.0f;

    const int lx = tid & 63;
    const int rowoff = tid >> 6;      // 0..7
    const int gx = tx0 + lx;

    auto proc = [&](int n, float2 fl, int gy, float r0, float r1, float r2) {
        const bool ok = (fl.x >= -(float)HALO) && (fl.x < (float)HALO) &&
                        (fl.y >= -(float)HALO) && (fl.y < (float)HALO);

        const float px = (float)gx + fl.x;
        const float py = (float)gy + fl.y;
        const float x0f = floorf(px);
        const float y0f = floorf(py);
        const float wx1 = px - x0f;
        const float wy1 = py - y0f;
        const float wx0 = 1.0f - wx1;
        const float wy0 = 1.0f - wy1;

        const bool vx0 = (x0f >= 0.0f) && (x0f <= (float)(IMG_W - 1));
        const bool vx1 = (x0f >= -1.0f) && (x0f <= (float)(IMG_W - 2));
        const bool vy0 = (y0f >= 0.0f) && (y0f <= (float)(IMG_H - 1));
        const bool vy1 = (y0f >= -1.0f) && (y0f <= (float)(IMG_H - 2));

        const float w00 = (vx0 && vy0) ? (wx0 * wy0) : 0.0f;
        const float w10 = (vx1 && vy0) ? (wx1 * wy0) : 0.0f;
        const float w01 = (vx0 && vy1) ? (wx0 * wy1) : 0.0f;
        const float w11 = (vx1 && vy1) ? (wx1 * wy1) : 0.0f;

        unsigned v00, v10, v01, v11;
        if (ok) {
            const int ri = ((int)y0f - by) * REG_W + ((int)x0f - bx);
            v00 = tile[ri];
            v10 = tile[ri + 1];
            v01 = tile[ri + REG_W];
            v11 = tile[ri + REG_W + 1];
        } else {
            // rare outlier (P ~ 1e-6/flow): clamped global reads of packed img
            const int x0i = (int)fminf(fmaxf(x0f, 0.0f), (float)(IMG_W - 1));
            const int x1i = (int)fminf(fmaxf(x0f + 1.0f, 0.0f), (float)(IMG_W - 1));
            const int y0i = (int)fminf(fmaxf(y0f, 0.0f), (float)(IMG_H - 1));
            const int y1i = (int)fminf(fmaxf(y0f + 1.0f, 0.0f), (float)(IMG_H - 1));
            v00 = img[y0i * IMG_W + x0i];
            v10 = img[y0i * IMG_W + x1i];
            v01 = img[y1i * IMG_W + x0i];
            v11 = img[y1i * IMG_W + x1i];
        }

        const float e0 = (float)(v00 & 255u) * w00 + (float)(v10 & 255u) * w10 +
                         (float)(v01 & 255u) * w01 + (float)(v11 & 255u) * w11;
        const float e1 = (float)((v00 >> 8) & 255u) * w00 + (float)((v10 >> 8) & 255u) * w10 +
                         (float)((v01 >> 8) & 255u) * w01 + (float)((v11 >> 8) & 255u) * w11;
        const float e2 = (float)((v00 >> 16) & 255u) * w00 + (float)((v10 >> 16) & 255u) * w10 +
                         (float)((v01 >> 16) & 255u) * w01 + (float)((v11 >> 16) & 255u) * w11;

        const float d0 = r0 - truncf(e0);
        const float d1 = r1 - truncf(e1);
        const float d2 = r2 - truncf(e2);
        acc[n] += d0 * d0 + d1 * d1 + d2 * d2;
    };

    // --- main loop: 2 pairs of 8-row iterations; 16 clustered loads per pair.
    // Row validity: only (last row-tile, iteration 3) is out of image.
#pragma unroll
    for (int pr = 0; pr < 2; ++pr) {
        const int gyA = ty0 + pr * 16 + rowoff;      // always < IMG_H
        const int gyB = gyA + 8;
        const bool vB = (pr == 0) || (ty0 + 24 < IMG_H);  // block-uniform
        const int gyBl = vB ? gyB : gyA;             // clamped for the load
        const int pA = gyA * IMG_W + gx;
        const int pB = gyBl * IMG_W + gx;

        // issue ALL 16 independent loads, then fence against sinking
        const float2 a0 = flow[pA];
        const float2 a1 = flow[HW + pA];
        const float2 a2 = flow[2 * HW + pA];
        const float2 a3 = flow[3 * HW + pA];
        const float2 a4 = flow[4 * HW + pA];
        const float2 b0 = flow[pB];
        const float2 b1 = flow[HW + pB];
        const float2 b2 = flow[2 * HW + pB];
        const float2 b3 = flow[3 * HW + pB];
        const float2 b4 = flow[4 * HW + pB];
        const float ra0 = f2[pA];
        const float ra1 = f2[HW + pA];
        const float ra2 = f2[2 * HW + pA];
        const float rb0 = f2[pB];
        const float rb1 = f2[HW + pB];
        const float rb2 = f2[2 * HW + pB];
        asm volatile("" ::: "memory");

        proc(0, a0, gyA, ra0, ra1, ra2);
        proc(1, a1, gyA, ra0, ra1, ra2);
        proc(2, a2, gyA, ra0, ra1, ra2);
        proc(3, a3, gyA, ra0, ra1, ra2);
        proc(4, a4, gyA, ra0, ra1, ra2);
        if (vB) {
            proc(0, b0, gyB, rb0, rb1, rb2);
            proc(1, b1, gyB, rb0, rb1, rb2);
            proc(2, b2, gyB, rb0, rb1, rb2);
            proc(3, b3, gyB, rb0, rb1, rb2);
            proc(4, b4, gyB, rb0, rb1, rb2);
        }
    }

    // --- wave64 reduce, cross-wave LDS reduce, one atomic per block per flow
#pragma unroll
    for (int n = 0; n < NFLOW; ++n) {
#pragma unroll
        for (int off = 32; off > 0; off >>= 1)
            acc[n] += __shfl_down(acc[n], off, 64);
    }
    const int lane = threadIdx.x & 63;
    const int wid = threadIdx.x >> 6;
    if (lane == 0) {
#pragma unroll
        for (int n = 0; n < NFLOW; ++n) sacc[n][wid] = acc[n];
    }
    __syncthreads();

    if (tid == 0) {
#pragma unroll
        for (int n = 0; n < NFLOW; ++n) {
            float s = 0.0f;
#pragma unroll
            for (int w = 0; w < THREADS / 64; ++w) s += sacc[n][w];
            atomicAdd(&sums[n], s);
        }

        __threadfence();
        if (atomicAdd(counter, 1u) == (unsigned)(NBLOCKS - 1)) {
            __threadfence();
            double aggr = 0.0;
            for (int n = 0; n < NFLOW; ++n) {
                const float sn = __hip_atomic_load(&sums[n], __ATOMIC_RELAXED,
                                                   __HIP_MEMORY_SCOPE_AGENT);
                const double mse = (double)sn / (3.0 * (double)HW);
                const double psnr = 10.0 * log10(255.0 * 255.0 / mse);
                double wgt = 1.0;
                for (int k = 0; k < NFLOW - n; ++k) wgt *= 0.85;
                aggr += psnr * wgt;
            }
            out[0] = (float)(-aggr);
        }
    }
}

extern "C" void kernel_launch(void* const* d_in, const int* in_sizes, int n_in,
                              void* d_out, int out_size, void* d_ws, size_t ws_size,
                              hipStream_t stream) {
    const float* flow = (const float*)d_in[0];  // [5,1080,1920,2]
    const float* f1   = (const float*)d_in[1];  // [3,1080,1920]
    const float* f2   = (const float*)d_in[2];  // [3,1080,1920]
    float* out = (float*)d_out;

    float* sums = (float*)d_ws;                               // 5 floats @ 0
    unsigned int* counter = (unsigned int*)((char*)d_ws + 32);// u32 @ 32
    unsigned int* img = (unsigned int*)((char*)d_ws + 256);   // HW u32 @ 256 (~8.3 MB)

    hipMemsetAsync(d_ws, 0, 64, stream);

    pack_u8_kernel<<<(HW / 4 + 255) / 256, 256, 0, stream>>>(f1, (uint4*)img);
    psnr_mega_kernel<<<NBLOCKS, THREADS, 0, stream>>>(
        (const float2*)flow, img, f2, sums, counter, out);
}

// Round 10
// 258.421 us; speedup vs baseline: 1.1368x; 1.1368x over previous
//
#include <hip/hip_runtime.h>
#include <math.h>

#define IMG_H 1080
#define IMG_W 1920
#define NFLOW 5
#define HW (IMG_H * IMG_W)

#define TILE_W 64
#define TILE_H 32
#define HALO 24
#define REG_W (TILE_W + 2 * HALO)   // 112
#define REG_H (TILE_H + 2 * HALO)   // 80
#define THREADS 512
#define GRID_X (IMG_W / TILE_W)                 // 30
#define GRID_Y ((IMG_H + TILE_H - 1) / TILE_H)  // 34
#define NBLOCKS (GRID_X * GRID_Y)               // 1020

__device__ __forceinline__ unsigned pack3(float a, float b, float c) {
    const unsigned c0 = (unsigned)(int)(a + 0.5f);
    const unsigned c1 = (unsigned)(int)(b + 0.5f);
    const unsigned c2 = (unsigned)(int)(c + 0.5f);
    return c0 | (c1 << 8) | (c2 << 16);
}

// ---------- pre-pass: pack frame1 [3][H][W] f32 -> [H][W] u32 (u8 RGB), 4 px/thread ----------
__global__ __launch_bounds__(256) void pack_u8_kernel(const float* __restrict__ f1,
                                                      uint4* __restrict__ img4)
{
    const int q = blockIdx.x * 256 + threadIdx.x;   // quad index; HW % 4 == 0
    if (q >= HW / 4) return;
    const int gp = q * 4;
    const float4 c0 = *(const float4*)(f1 + gp);
    const float4 c1 = *(const float4*)(f1 + HW + gp);
    const float4 c2 = *(const float4*)(f1 + 2 * HW + gp);
    uint4 ov;
    ov.x = pack3(c0.x, c1.x, c2.x);
    ov.y = pack3(c0.y, c1.y, c2.y);
    ov.z = pack3(c0.z, c1.z, c2.z);
    ov.w = pack3(c0.w, c1.w, c2.w);
    img4[q] = ov;
}

// ---------- main: LDS-tiled warped-SSE, clustered loads, VGPR headroom for MLP ----------
// __launch_bounds__(512,4): VGPR cap 128 (not 64) so the 16 clustered payload
// values stay in registers instead of spilling to scratch (round-9 failure:
// 181 MB scratch WRITE_SIZE at the (512,8)/32-VGPR posture).
__global__ __launch_bounds__(THREADS, 4) void psnr_mega_kernel(
    const float2* __restrict__ flow,        // [N][H][W] float2
    const unsigned int* __restrict__ img,   // [H][W] packed u8 RGB
    const float* __restrict__ f2,           // [3][H][W]
    float* __restrict__ sums,               // [5] zeroed
    unsigned int* __restrict__ counter,     // [1] zeroed
    float* __restrict__ out)                // [1]
{
    __shared__ __align__(16) unsigned int tile[REG_H * REG_W];  // 35840 B
    __shared__ float sacc[NFLOW][THREADS / 64];

    // --- bijective XCD-chunked swizzle (1020 = 8*127 + 4) ---
    const int wg = blockIdx.x;
    const int xcd = wg & 7;
    const int idx = wg >> 3;
    const int q = NBLOCKS >> 3;        // 127
    const int rr = NBLOCKS & 7;        // 4
    const int wgid = (xcd < rr ? xcd * (q + 1) : rr * (q + 1) + (xcd - rr) * q) + idx;
    const int tyb = wgid / GRID_X;
    const int txb = wgid - tyb * GRID_X;

    const int tx0 = txb * TILE_W;
    const int ty0 = tyb * TILE_H;
    const int bx = tx0 - HALO;
    const int by = ty0 - HALO;
    const int tid = threadIdx.x;

    // --- stage packed-u8 tile from img: 1 uint4 load per 4 texels ---
    for (int qi = tid; qi < (REG_H * REG_W) / 4; qi += THREADS) {
        const int ry = qi / (REG_W / 4);
        const int rx = (qi - ry * (REG_W / 4)) * 4;
        const int gy = by + ry;
        const int gx0 = bx + rx;
        uint4 ov = {0u, 0u, 0u, 0u};
        if ((unsigned)gy < (unsigned)IMG_H) {
            if (gx0 >= 0 && gx0 + 3 < IMG_W) {
                ov = *(const uint4*)(img + gy * IMG_W + gx0);   // bx%4==0 -> aligned
            } else {
#pragma unroll
                for (int j = 0; j < 4; ++j) {
                    const int gx = gx0 + j;
                    unsigned v = 0u;
                    if ((unsigned)gx < (unsigned)IMG_W) v = img[gy * IMG_W + gx];
                    ((unsigned*)&ov)[j] = v;
                }
            }
        }
        *(uint4*)&tile[ry * REG_W + rx] = ov;   // ds_write_b128, 16B-aligned
    }
    __syncthreads();

    float acc[NFLOW];
#pragma unroll
    for (int n = 0; n < NFLOW; ++n) acc[n] = 0.0f;

    const int lx = tid & 63;
    const int rowoff = tid >> 6;      // 0..7
    const int gx = tx0 + lx;

    auto proc = [&](int n, float2 fl, int gy, float r0, float r1, float r2) {
        const bool ok = (fl.x >= -(float)HALO) && (fl.x < (float)HALO) &&
                        (fl.y >= -(float)HALO) && (fl.y < (float)HALO);

        const float px = (float)gx + fl.x;
        const float py = (float)gy + fl.y;
        const float x0f = floorf(px);
        const float y0f = floorf(py);
        const float wx1 = px - x0f;
        const float wy1 = py - y0f;
        const float wx0 = 1.0f - wx1;
        const float wy0 = 1.0f - wy1;

        const bool vx0 = (x0f >= 0.0f) && (x0f <= (float)(IMG_W - 1));
        const bool vx1 = (x0f >= -1.0f) && (x0f <= (float)(IMG_W - 2));
        const bool vy0 = (y0f >= 0.0f) && (y0f <= (float)(IMG_H - 1));
        const bool vy1 = (y0f >= -1.0f) && (y0f <= (float)(IMG_H - 2));

        const float w00 = (vx0 && vy0) ? (wx0 * wy0) : 0.0f;
        const float w10 = (vx1 && vy0) ? (wx1 * wy0) : 0.0f;
        const float w01 = (vx0 && vy1) ? (wx0 * wy1) : 0.0f;
        const float w11 = (vx1 && vy1) ? (wx1 * wy1) : 0.0f;

        unsigned v00, v10, v01, v11;
        if (ok) {
            const int ri = ((int)y0f - by) * REG_W + ((int)x0f - bx);
            v00 = tile[ri];
            v10 = tile[ri + 1];
            v01 = tile[ri + REG_W];
            v11 = tile[ri + REG_W + 1];
        } else {
            // rare outlier (P ~ 1e-6/flow): clamped global reads of packed img
            const int x0i = (int)fminf(fmaxf(x0f, 0.0f), (float)(IMG_W - 1));
            const int x1i = (int)fminf(fmaxf(x0f + 1.0f, 0.0f), (float)(IMG_W - 1));
            const int y0i = (int)fminf(fmaxf(y0f, 0.0f), (float)(IMG_H - 1));
            const int y1i = (int)fminf(fmaxf(y0f + 1.0f, 0.0f), (float)(IMG_H - 1));
            v00 = img[y0i * IMG_W + x0i];
            v10 = img[y0i * IMG_W + x1i];
            v01 = img[y1i * IMG_W + x0i];
            v11 = img[y1i * IMG_W + x1i];
        }

        const float e0 = (float)(v00 & 255u) * w00 + (float)(v10 & 255u) * w10 +
                         (float)(v01 & 255u) * w01 + (float)(v11 & 255u) * w11;
        const float e1 = (float)((v00 >> 8) & 255u) * w00 + (float)((v10 >> 8) & 255u) * w10 +
                         (float)((v01 >> 8) & 255u) * w01 + (float)((v11 >> 8) & 255u) * w11;
        const float e2 = (float)((v00 >> 16) & 255u) * w00 + (float)((v10 >> 16) & 255u) * w10 +
                         (float)((v01 >> 16) & 255u) * w01 + (float)((v11 >> 16) & 255u) * w11;

        const float d0 = r0 - truncf(e0);
        const float d1 = r1 - truncf(e1);
        const float d2 = r2 - truncf(e2);
        acc[n] += d0 * d0 + d1 * d1 + d2 * d2;
    };

    // --- main loop: 2 pairs of 8-row iterations; 16 clustered loads per pair.
#pragma unroll
    for (int pr = 0; pr < 2; ++pr) {
        const int gyA = ty0 + pr * 16 + rowoff;      // always < IMG_H
        const int gyB = gyA + 8;
        const bool vB = (pr == 0) || (ty0 + 24 < IMG_H);  // block-uniform
        const int gyBl = vB ? gyB : gyA;             // clamped for the load
        const int pA = gyA * IMG_W + gx;
        const int pB = gyBl * IMG_W + gx;

        // issue ALL 16 independent loads, then fence against sinking
        const float2 a0 = flow[pA];
        const float2 a1 = flow[HW + pA];
        const float2 a2 = flow[2 * HW + pA];
        const float2 a3 = flow[3 * HW + pA];
        const float2 a4 = flow[4 * HW + pA];
        const float2 b0 = flow[pB];
        const float2 b1 = flow[HW + pB];
        const float2 b2 = flow[2 * HW + pB];
        const float2 b3 = flow[3 * HW + pB];
        const float2 b4 = flow[4 * HW + pB];
        const float ra0 = f2[pA];
        const float ra1 = f2[HW + pA];
        const float ra2 = f2[2 * HW + pA];
        const float rb0 = f2[pB];
        const float rb1 = f2[HW + pB];
        const float rb2 = f2[2 * HW + pB];
        asm volatile("" ::: "memory");

        proc(0, a0, gyA, ra0, ra1, ra2);
        proc(1, a1, gyA, ra0, ra1, ra2);
        proc(2, a2, gyA, ra0, ra1, ra2);
        proc(3, a3, gyA, ra0, ra1, ra2);
        proc(4, a4, gyA, ra0, ra1, ra2);
        if (vB) {
            proc(0, b0, gyB, rb0, rb1, rb2);
            proc(1, b1, gyB, rb0, rb1, rb2);
            proc(2, b2, gyB, rb0, rb1, rb2);
            proc(3, b3, gyB, rb0, rb1, rb2);
            proc(4, b4, gyB, rb0, rb1, rb2);
        }
    }

    // --- wave64 reduce, cross-wave LDS reduce, one atomic per block per flow
#pragma unroll
    for (int n = 0; n < NFLOW; ++n) {
#pragma unroll
        for (int off = 32; off > 0; off >>= 1)
            acc[n] += __shfl_down(acc[n], off, 64);
    }
    const int lane = threadIdx.x & 63;
    const int wid = threadIdx.x >> 6;
    if (lane == 0) {
#pragma unroll
        for (int n = 0; n < NFLOW; ++n) sacc[n][wid] = acc[n];
    }
    __syncthreads();

    if (tid == 0) {
#pragma unroll
        for (int n = 0; n < NFLOW; ++n) {
            float s = 0.0f;
#pragma unroll
            for (int w = 0; w < THREADS / 64; ++w) s += sacc[n][w];
            atomicAdd(&sums[n], s);
        }

        __threadfence();
        if (atomicAdd(counter, 1u) == (unsigned)(NBLOCKS - 1)) {
            __threadfence();
            double aggr = 0.0;
            for (int n = 0; n < NFLOW; ++n) {
                const float sn = __hip_atomic_load(&sums[n], __ATOMIC_RELAXED,
                                                   __HIP_MEMORY_SCOPE_AGENT);
                const double mse = (double)sn / (3.0 * (double)HW);
                const double psnr = 10.0 * log10(255.0 * 255.0 / mse);
                double wgt = 1.0;
                for (int k = 0; k < NFLOW - n; ++k) wgt *= 0.85;
                aggr += psnr * wgt;
            }
            out[0] = (float)(-aggr);
        }
    }
}

extern "C" void kernel_launch(void* const* d_in, const int* in_sizes, int n_in,
                              void* d_out, int out_size, void* d_ws, size_t ws_size,
                              hipStream_t stream) {
    const float* flow = (const float*)d_in[0];  // [5,1080,1920,2]
    const float* f1   = (const float*)d_in[1];  // [3,1080,1920]
    const float* f2   = (const float*)d_in[2];  // [3,1080,1920]
    float* out = (float*)d_out;

    float* sums = (float*)d_ws;                               // 5 floats @ 0
    unsigned int* counter = (unsigned int*)((char*)d_ws + 32);// u32 @ 32
    unsigned int* img = (unsigned int*)((char*)d_ws + 256);   // HW u32 @ 256 (~8.3 MB)

    hipMemsetAsync(d_ws, 0, 64, stream);

    pack_u8_kernel<<<(HW / 4 + 255) / 256, 256, 0, stream>>>(f1, (uint4*)img);
    psnr_mega_kernel<<<NBLOCKS, THREADS, 0, stream>>>(
        (const float2*)flow, img, f2, sums, counter, out);
}